// Round 6
// baseline (196.376 us; speedup 1.0000x reference)
//
#include <hip/hip_runtime.h>
#include <math.h>

// Problem constants
#define BB 128
#define KK 32
#define JJ 1152
#define II 8
#define ZZ 16

#define JCB 32              // j's per block (hot kernels)
#define NJC (JJ / JCB)      // 36 chunks
#define JPW (JCB / 4)       // 8 j's per wave (4 waves/block)

#define WS_FLOATS (JCB * II * ZZ)   // 4096 floats = 16 KB LDS per block

// Workspace layout (floats): accumulators first (memset), then xT, then E.
#define N_USUM (KK * ZZ * BB)   // [k][z][b]   65536
#define N_S    (JJ * BB)        // [j][b]     147456
#define N_SACC (KK * ZZ * BB)   // [k][z][b]   65536
#define N_ACC  (N_USUM + N_S + N_SACC)
#define N_XT   (JJ * BB * II)   // [j][b][i] 1179648
#define N_E    (KK * JJ * BB)   // [k][j][b] 4718592

// ---- Transpose: x[b][j][i] -> xT[j][b][i] (float4 granularity) ----
extern "C" __global__ __launch_bounds__(256)
void kT(const float* __restrict__ x, float* __restrict__ xT) {
    int idx = blockIdx.x * 256 + threadIdx.x;       // float4 index in xT
    int j  = idx >> 8;            // / (BB*2)
    int r  = idx & 255;
    int b  = r >> 1;
    int i4 = r & 1;
    float4 v = ((const float4*)x)[((size_t)b * JJ + j) * 2 + i4];
    ((float4*)xT)[idx] = v;       // fully coalesced write
}

// Stage this block's W slice (32 j x 8 i x 16 z = 16 KB) into LDS, coalesced.
__device__ __forceinline__ void stage_W(const float* __restrict__ W,
                                        float* Ws, int k, int jcb) {
    const float4* Wg = (const float4*)(W + ((size_t)k * JJ + jcb) * II * ZZ);
    float4* Wl = (float4*)Ws;
#pragma unroll
    for (int it = 0; it < 4; ++it) {
        int f4 = it * 256 + threadIdx.x;   // 0..1023
        Wl[f4] = Wg[f4];
    }
}

// ---- Pass A: usum[k][z][b] = sum_j u[b,k,j,z]  (B2=2 b-blocking) ----
extern "C" __global__ __launch_bounds__(256)
void kA(const float* __restrict__ xT, const float* __restrict__ W,
        float* __restrict__ usum) {
    __shared__ float Ws[WS_FLOATS];
    const int jcb = blockIdx.x * JCB;
    const int k   = blockIdx.y;
    stage_W(W, Ws, k, jcb);
    __syncthreads();

    const int t  = threadIdx.x;
    const int w  = t >> 6;
    const int lb = t & 63;     // b1 = lb, b2 = lb + 64

    float a1[ZZ], a2[ZZ];
#pragma unroll
    for (int z = 0; z < ZZ; ++z) { a1[z] = 0.f; a2[z] = 0.f; }

    const int j0 = jcb + w * JPW;
#pragma unroll
    for (int jl = 0; jl < JPW; ++jl) {
        const float4* xp1 = (const float4*)(xT + ((size_t)(j0 + jl) * BB + lb) * II);
        const float4* xp2 = xp1 + (64 * II / 4);
        float4 xa1 = xp1[0], xb1 = xp1[1];
        float4 xa2 = xp2[0], xb2 = xp2[1];
        const float x1[II] = {xa1.x, xa1.y, xa1.z, xa1.w, xb1.x, xb1.y, xb1.z, xb1.w};
        const float x2[II] = {xa2.x, xa2.y, xa2.z, xa2.w, xb2.x, xb2.y, xb2.z, xb2.w};
        const float* Wj = Ws + (w * JPW + jl) * II * ZZ;
#pragma unroll
        for (int i = 0; i < II; ++i) {
            const float4* wp = (const float4*)(Wj + i * ZZ);  // ds_read_b128 broadcast
            float4 w0 = wp[0], w1 = wp[1], w2 = wp[2], w3 = wp[3];
            float v1 = x1[i], v2 = x2[i];
            a1[0]  = fmaf(v1, w0.x, a1[0]);  a2[0]  = fmaf(v2, w0.x, a2[0]);
            a1[1]  = fmaf(v1, w0.y, a1[1]);  a2[1]  = fmaf(v2, w0.y, a2[1]);
            a1[2]  = fmaf(v1, w0.z, a1[2]);  a2[2]  = fmaf(v2, w0.z, a2[2]);
            a1[3]  = fmaf(v1, w0.w, a1[3]);  a2[3]  = fmaf(v2, w0.w, a2[3]);
            a1[4]  = fmaf(v1, w1.x, a1[4]);  a2[4]  = fmaf(v2, w1.x, a2[4]);
            a1[5]  = fmaf(v1, w1.y, a1[5]);  a2[5]  = fmaf(v2, w1.y, a2[5]);
            a1[6]  = fmaf(v1, w1.z, a1[6]);  a2[6]  = fmaf(v2, w1.z, a2[6]);
            a1[7]  = fmaf(v1, w1.w, a1[7]);  a2[7]  = fmaf(v2, w1.w, a2[7]);
            a1[8]  = fmaf(v1, w2.x, a1[8]);  a2[8]  = fmaf(v2, w2.x, a2[8]);
            a1[9]  = fmaf(v1, w2.y, a1[9]);  a2[9]  = fmaf(v2, w2.y, a2[9]);
            a1[10] = fmaf(v1, w2.z, a1[10]); a2[10] = fmaf(v2, w2.z, a2[10]);
            a1[11] = fmaf(v1, w2.w, a1[11]); a2[11] = fmaf(v2, w2.w, a2[11]);
            a1[12] = fmaf(v1, w3.x, a1[12]); a2[12] = fmaf(v2, w3.x, a2[12]);
            a1[13] = fmaf(v1, w3.y, a1[13]); a2[13] = fmaf(v2, w3.y, a2[13]);
            a1[14] = fmaf(v1, w3.z, a1[14]); a2[14] = fmaf(v2, w3.z, a2[14]);
            a1[15] = fmaf(v1, w3.w, a1[15]); a2[15] = fmaf(v2, w3.w, a2[15]);
        }
    }
#pragma unroll
    for (int z = 0; z < ZZ; ++z) {
        unsafeAtomicAdd(&usum[(k * ZZ + z) * BB + lb],      a1[z]);
        unsafeAtomicAdd(&usum[(k * ZZ + z) * BB + lb + 64], a2[z]);
    }
}

// ---- Pass B: E[k][j][b] = exp(dot_z(u,usum)/4); S[j][b] += E ----
// Register-light V-form: dp = sum_i x_i * ( sum_z W[i][z]*us[z] )
extern "C" __global__ __launch_bounds__(256)
void kB(const float* __restrict__ xT, const float* __restrict__ W,
        const float* __restrict__ usum, float* __restrict__ S,
        float* __restrict__ E) {
    __shared__ float Ws[WS_FLOATS];
    const int jcb = blockIdx.x * JCB;
    const int k   = blockIdx.y;
    stage_W(W, Ws, k, jcb);
    __syncthreads();

    const int t  = threadIdx.x;
    const int w  = t >> 6;
    const int lb = t & 63;

    float us1[ZZ], us2[ZZ];
#pragma unroll
    for (int z = 0; z < ZZ; ++z) {
        us1[z] = usum[(k * ZZ + z) * BB + lb];
        us2[z] = usum[(k * ZZ + z) * BB + lb + 64];
    }

    const int j0 = jcb + w * JPW;
#pragma unroll
    for (int jl = 0; jl < JPW; ++jl) {
        const int j = j0 + jl;
        const float4* xp1 = (const float4*)(xT + ((size_t)j * BB + lb) * II);
        const float4* xp2 = xp1 + (64 * II / 4);
        float4 xa1 = xp1[0], xb1 = xp1[1];
        float4 xa2 = xp2[0], xb2 = xp2[1];
        const float x1[II] = {xa1.x, xa1.y, xa1.z, xa1.w, xb1.x, xb1.y, xb1.z, xb1.w};
        const float x2[II] = {xa2.x, xa2.y, xa2.z, xa2.w, xb2.x, xb2.y, xb2.z, xb2.w};
        const float* Wj = Ws + (w * JPW + jl) * II * ZZ;
        float dp1 = 0.f, dp2 = 0.f;
#pragma unroll
        for (int i = 0; i < II; ++i) {
            const float4* wp = (const float4*)(Wj + i * ZZ);
            float4 w0 = wp[0], w1 = wp[1], w2 = wp[2], w3 = wp[3];
            float v1 = w0.x * us1[0];
            v1 = fmaf(w0.y, us1[1],  v1); v1 = fmaf(w0.z, us1[2],  v1);
            v1 = fmaf(w0.w, us1[3],  v1); v1 = fmaf(w1.x, us1[4],  v1);
            v1 = fmaf(w1.y, us1[5],  v1); v1 = fmaf(w1.z, us1[6],  v1);
            v1 = fmaf(w1.w, us1[7],  v1); v1 = fmaf(w2.x, us1[8],  v1);
            v1 = fmaf(w2.y, us1[9],  v1); v1 = fmaf(w2.z, us1[10], v1);
            v1 = fmaf(w2.w, us1[11], v1); v1 = fmaf(w3.x, us1[12], v1);
            v1 = fmaf(w3.y, us1[13], v1); v1 = fmaf(w3.z, us1[14], v1);
            v1 = fmaf(w3.w, us1[15], v1);
            float v2 = w0.x * us2[0];
            v2 = fmaf(w0.y, us2[1],  v2); v2 = fmaf(w0.z, us2[2],  v2);
            v2 = fmaf(w0.w, us2[3],  v2); v2 = fmaf(w1.x, us2[4],  v2);
            v2 = fmaf(w1.y, us2[5],  v2); v2 = fmaf(w1.z, us2[6],  v2);
            v2 = fmaf(w1.w, us2[7],  v2); v2 = fmaf(w2.x, us2[8],  v2);
            v2 = fmaf(w2.y, us2[9],  v2); v2 = fmaf(w2.z, us2[10], v2);
            v2 = fmaf(w2.w, us2[11], v2); v2 = fmaf(w3.x, us2[12], v2);
            v2 = fmaf(w3.y, us2[13], v2); v2 = fmaf(w3.z, us2[14], v2);
            v2 = fmaf(w3.w, us2[15], v2);
            dp1 = fmaf(x1[i], v1, dp1);
            dp2 = fmaf(x2[i], v2, dp2);
        }
        float e1 = __expf(dp1 * 0.25f);   // / sqrt(Z=16)
        float e2 = __expf(dp2 * 0.25f);
        E[((size_t)k * JJ + j) * BB + lb]      = e1;
        E[((size_t)k * JJ + j) * BB + lb + 64] = e2;
        unsafeAtomicAdd(&S[j * BB + lb],      e1);
        unsafeAtomicAdd(&S[j * BB + lb + 64], e2);
    }
}

// ---- Pass C: sacc[k][z][b] += sum_j u[b,k,j,z] * c[b,k,j]
//      folded: sc[z] += (c * x_i) * W[i][z] ----
extern "C" __global__ __launch_bounds__(256)
void kC(const float* __restrict__ xT, const float* __restrict__ W,
        const float* __restrict__ bias, const float* __restrict__ S,
        const float* __restrict__ E, float* __restrict__ sacc) {
    __shared__ float Ws[WS_FLOATS];
    const int jcb = blockIdx.x * JCB;
    const int k   = blockIdx.y;
    stage_W(W, Ws, k, jcb);
    __syncthreads();

    const int t  = threadIdx.x;
    const int w  = t >> 6;
    const int lb = t & 63;

    float sc1[ZZ], sc2[ZZ];
#pragma unroll
    for (int z = 0; z < ZZ; ++z) { sc1[z] = 0.f; sc2[z] = 0.f; }

    const int j0 = jcb + w * JPW;
#pragma unroll
    for (int jl = 0; jl < JPW; ++jl) {
        const int j = j0 + jl;
        const float4* xp1 = (const float4*)(xT + ((size_t)j * BB + lb) * II);
        const float4* xp2 = xp1 + (64 * II / 4);
        float4 xa1 = xp1[0], xb1 = xp1[1];
        float4 xa2 = xp2[0], xb2 = xp2[1];
        float e1 = E[((size_t)k * JJ + j) * BB + lb];
        float e2 = E[((size_t)k * JJ + j) * BB + lb + 64];
        float Sv1 = S[j * BB + lb];
        float Sv2 = S[j * BB + lb + 64];
        float bj  = bias[k * JJ + j];                 // uniform (tiny)
        float c1 = fmaf(e1, __builtin_amdgcn_rcpf(Sv1), bj);
        float c2 = fmaf(e2, __builtin_amdgcn_rcpf(Sv2), bj);
        const float x1[II] = {xa1.x * c1, xa1.y * c1, xa1.z * c1, xa1.w * c1,
                              xb1.x * c1, xb1.y * c1, xb1.z * c1, xb1.w * c1};
        const float x2[II] = {xa2.x * c2, xa2.y * c2, xa2.z * c2, xa2.w * c2,
                              xb2.x * c2, xb2.y * c2, xb2.z * c2, xb2.w * c2};
        const float* Wj = Ws + (w * JPW + jl) * II * ZZ;
#pragma unroll
        for (int i = 0; i < II; ++i) {
            const float4* wp = (const float4*)(Wj + i * ZZ);
            float4 w0 = wp[0], w1 = wp[1], w2 = wp[2], w3 = wp[3];
            float v1 = x1[i], v2 = x2[i];
            sc1[0]  = fmaf(v1, w0.x, sc1[0]);  sc2[0]  = fmaf(v2, w0.x, sc2[0]);
            sc1[1]  = fmaf(v1, w0.y, sc1[1]);  sc2[1]  = fmaf(v2, w0.y, sc2[1]);
            sc1[2]  = fmaf(v1, w0.z, sc1[2]);  sc2[2]  = fmaf(v2, w0.z, sc2[2]);
            sc1[3]  = fmaf(v1, w0.w, sc1[3]);  sc2[3]  = fmaf(v2, w0.w, sc2[3]);
            sc1[4]  = fmaf(v1, w1.x, sc1[4]);  sc2[4]  = fmaf(v2, w1.x, sc2[4]);
            sc1[5]  = fmaf(v1, w1.y, sc1[5]);  sc2[5]  = fmaf(v2, w1.y, sc2[5]);
            sc1[6]  = fmaf(v1, w1.z, sc1[6]);  sc2[6]  = fmaf(v2, w1.z, sc2[6]);
            sc1[7]  = fmaf(v1, w1.w, sc1[7]);  sc2[7]  = fmaf(v2, w1.w, sc2[7]);
            sc1[8]  = fmaf(v1, w2.x, sc1[8]);  sc2[8]  = fmaf(v2, w2.x, sc2[8]);
            sc1[9]  = fmaf(v1, w2.y, sc1[9]);  sc2[9]  = fmaf(v2, w2.y, sc2[9]);
            sc1[10] = fmaf(v1, w2.z, sc1[10]); sc2[10] = fmaf(v2, w2.z, sc2[10]);
            sc1[11] = fmaf(v1, w2.w, sc1[11]); sc2[11] = fmaf(v2, w2.w, sc2[11]);
            sc1[12] = fmaf(v1, w3.x, sc1[12]); sc2[12] = fmaf(v2, w3.x, sc2[12]);
            sc1[13] = fmaf(v1, w3.y, sc1[13]); sc2[13] = fmaf(v2, w3.y, sc2[13]);
            sc1[14] = fmaf(v1, w3.z, sc1[14]); sc2[14] = fmaf(v2, w3.z, sc2[14]);
            sc1[15] = fmaf(v1, w3.w, sc1[15]); sc2[15] = fmaf(v2, w3.w, sc2[15]);
        }
    }
#pragma unroll
    for (int z = 0; z < ZZ; ++z) {
        unsafeAtomicAdd(&sacc[(k * ZZ + z) * BB + lb],      sc1[z]);
        unsafeAtomicAdd(&sacc[(k * ZZ + z) * BB + lb + 64], sc2[z]);
    }
}

// ---- Pass D: squash, sacc[k][z][b] -> out[b][k][z] ----
extern "C" __global__ __launch_bounds__(256)
void kD(const float* __restrict__ sacc, float* __restrict__ out) {
    int p = blockIdx.x * blockDim.x + threadIdx.x;
    if (p >= KK * BB) return;
    int k = p >> 7;       // /128
    int b = p & 127;
    float v[ZZ];
    float nsq = 0.f;
#pragma unroll
    for (int z = 0; z < ZZ; ++z) {
        v[z] = sacc[(k * ZZ + z) * BB + b];   // coalesced per z
        nsq  = fmaf(v[z], v[z], nsq);
    }
    float n = sqrtf(nsq);
    float scale = (1.f - 1.f / (__expf(n) + 1e-20f)) / (n + 1e-20f);
#pragma unroll
    for (int z = 0; z < ZZ; ++z)
        out[((size_t)b * KK + k) * ZZ + z] = v[z] * scale;
}

extern "C" void kernel_launch(void* const* d_in, const int* in_sizes, int n_in,
                              void* d_out, int out_size, void* d_ws, size_t ws_size,
                              hipStream_t stream) {
    const float* x    = (const float*)d_in[0];
    const float* W    = (const float*)d_in[1];
    const float* bias = (const float*)d_in[2];
    float*       out  = (float*)d_out;

    float* ws    = (float*)d_ws;
    float* usum  = ws;                       // [K][Z][B]
    float* S     = ws + N_USUM;              // [J][B]
    float* saccp = ws + N_USUM + N_S;        // [K][Z][B]
    float* xT    = ws + N_ACC;               // [J][B][I]
    float* E     = ws + N_ACC + N_XT;        // [K][J][B]

    hipMemsetAsync(d_ws, 0, (size_t)N_ACC * sizeof(float), stream);

    kT<<<(N_XT / 4) / 256, 256, 0, stream>>>(x, xT);

    dim3 grid(NJC, KK);
    kA<<<grid, 256, 0, stream>>>(xT, W, usum);
    kB<<<grid, 256, 0, stream>>>(xT, W, usum, S, E);
    kC<<<grid, 256, 0, stream>>>(xT, W, bias, S, E, saccp);
    kD<<<(KK * BB + 255) / 256, 256, 0, stream>>>(saccp, out);
}

// Round 7
// 162.887 us; speedup vs baseline: 1.2056x; 1.2056x over previous
//
#include <hip/hip_runtime.h>
#include <hip/hip_bf16.h>
#include <math.h>

// Problem constants
#define BB 128
#define KK 32
#define JJ 1152
#define II 8
#define ZZ 16

typedef __attribute__((ext_vector_type(8))) short short8;
typedef __attribute__((ext_vector_type(4))) float floatx4;

// Workspace layout (floats): accumulators (memset), E, then bf16 buffers.
#define N_USUM (KK * ZZ * BB)   // [k][z][b]   65536
#define N_S    (JJ * BB)        // [j][b]     147456
#define N_SACC (KK * ZZ * BB)   // [k][z][b]   65536
#define N_ACC  (N_USUM + N_S + N_SACC)
#define N_E    (KK * JJ * BB)   // [k][j][b]  4718592 floats
#define N_XBF  (JJ * BB * II)   // bf16 elems 1179648
#define N_WT   (KK * JJ * ZZ * II) // bf16 elems 4718592

// ---- Prep: x[b][j][i] fp32 -> x_bf[j][b][i] bf16 ----
extern "C" __global__ __launch_bounds__(256)
void kX(const float* __restrict__ x, __hip_bfloat16* __restrict__ xbf) {
    int idx = blockIdx.x * 256 + threadIdx.x;    // [0, J*B)
    int j_in = idx & 15;
    int rest = idx >> 4;
    int b    = rest & 127;
    int j    = (rest >> 7) * 16 + j_in;
    const float4* xp = (const float4*)(x + ((size_t)b * JJ + j) * II);
    float4 a = xp[0], c = xp[1];
    union { short8 v; __hip_bfloat16 h[8]; } u;
    u.h[0] = __float2bfloat16(a.x); u.h[1] = __float2bfloat16(a.y);
    u.h[2] = __float2bfloat16(a.z); u.h[3] = __float2bfloat16(a.w);
    u.h[4] = __float2bfloat16(c.x); u.h[5] = __float2bfloat16(c.y);
    u.h[6] = __float2bfloat16(c.z); u.h[7] = __float2bfloat16(c.w);
    *(short8*)(xbf + ((size_t)j * BB + b) * II) = u.v;
}

// ---- Prep: W[k][j][i][z] fp32 -> Wt[k][j][z][i] bf16 ----
extern "C" __global__ __launch_bounds__(256)
void kW(const float* __restrict__ W, __hip_bfloat16* __restrict__ Wt) {
    int idx = blockIdx.x * 256 + threadIdx.x;    // [0, K*J*16)
    int z    = idx & 15;
    int rest = idx >> 4;                         // [0, K*J)
    int j    = rest % JJ;
    int k    = rest / JJ;
    const float* src = W + (((size_t)k * JJ + j) * II) * ZZ + z;
    union { short8 v; __hip_bfloat16 h[8]; } u;
#pragma unroll
    for (int i = 0; i < II; ++i) u.h[i] = __float2bfloat16(src[i * ZZ]);
    *(short8*)(Wt + (((size_t)k * JJ + j) * ZZ + z) * II) = u.v;
}

// ---- Pass A: usum[k][z][b] = sum_{j,i} x*W  (j-quads packed into K=32) ----
// MFMA: M=z(16), N=b(16), K=32 = 4 j x 8 i. D lane: b=lane&15, z=(lane>>4)*4+r.
extern "C" __global__ __launch_bounds__(64)
void kA(const __hip_bfloat16* __restrict__ xbf,
        const __hip_bfloat16* __restrict__ Wt, float* __restrict__ usum) {
    const int bt = blockIdx.x;          // 0..7  b-tile
    const int k  = blockIdx.y;          // 0..31
    const int js = blockIdx.z;          // 0..15 (18 j-quads each)
    const int l  = threadIdx.x;
    const int n  = l & 15;              // A: z-row ; B: b-col
    const int g  = l >> 4;              // K-group = j within quad
    const int b  = bt * 16 + n;

    floatx4 acc = {0.f, 0.f, 0.f, 0.f};
    for (int q = 0; q < 18; ++q) {
        int j = (js * 18 + q) * 4 + g;
        short8 a  = *(const short8*)(Wt  + (((size_t)k * JJ + j) * ZZ + n) * II);
        short8 xv = *(const short8*)(xbf + ((size_t)j * BB + b) * II);
        acc = __builtin_amdgcn_mfma_f32_16x16x32_bf16(a, xv, acc, 0, 0, 0);
    }
#pragma unroll
    for (int r = 0; r < 4; ++r)
        unsafeAtomicAdd(&usum[(k * ZZ + g * 4 + r) * BB + b], acc[r]);
}

// ---- Pass B: E[k][j][b] = exp(dp/4), S[j][b] += E ----
// Per-j MFMA with j duplicated across K-groups -> D = 4*u. dp scale 0.25/4.
extern "C" __global__ __launch_bounds__(64)
void kB(const __hip_bfloat16* __restrict__ xbf,
        const __hip_bfloat16* __restrict__ Wt, const float* __restrict__ usum,
        float* __restrict__ S, float* __restrict__ E) {
    const int bt = blockIdx.x;
    const int k  = blockIdx.y;
    const int js = blockIdx.z;          // 0..17, 64 j each
    const int l  = threadIdx.x;
    const int n  = l & 15;
    const int g  = l >> 4;
    const int b  = bt * 16 + n;

    float us[4];
#pragma unroll
    for (int r = 0; r < 4; ++r) us[r] = usum[(k * ZZ + g * 4 + r) * BB + b];

    for (int jl = 0; jl < 64; ++jl) {
        int j = js * 64 + jl;
        short8 a  = *(const short8*)(Wt  + (((size_t)k * JJ + j) * ZZ + n) * II);
        short8 xv = *(const short8*)(xbf + ((size_t)j * BB + b) * II);
        floatx4 c0 = {0.f, 0.f, 0.f, 0.f};
        floatx4 u4 = __builtin_amdgcn_mfma_f32_16x16x32_bf16(a, xv, c0, 0, 0, 0);
        float dp = u4[0] * us[0];
        dp = fmaf(u4[1], us[1], dp);
        dp = fmaf(u4[2], us[2], dp);
        dp = fmaf(u4[3], us[3], dp);
        dp += __shfl_xor(dp, 16);
        dp += __shfl_xor(dp, 32);
        float e = __expf(dp * 0.0625f);      // 0.25 (softmax scale) * 0.25 (D=4u)
        if (g == 0) {
            E[((size_t)k * JJ + j) * BB + b] = e;
            unsafeAtomicAdd(&S[j * BB + b], e);
        }
    }
}

// ---- Pass C: sacc[k][z][b] += sum_j u * (E/S + bias) ----
extern "C" __global__ __launch_bounds__(64)
void kC(const __hip_bfloat16* __restrict__ xbf,
        const __hip_bfloat16* __restrict__ Wt, const float* __restrict__ bias,
        const float* __restrict__ S, const float* __restrict__ E,
        float* __restrict__ sacc) {
    const int bt = blockIdx.x;
    const int k  = blockIdx.y;
    const int js = blockIdx.z;          // 0..11, 96 j each
    const int l  = threadIdx.x;
    const int n  = l & 15;
    const int g  = l >> 4;
    const int b  = bt * 16 + n;

    float sc[4] = {0.f, 0.f, 0.f, 0.f};
    for (int jl = 0; jl < 96; ++jl) {
        int j = js * 96 + jl;
        short8 a  = *(const short8*)(Wt  + (((size_t)k * JJ + j) * ZZ + n) * II);
        short8 xv = *(const short8*)(xbf + ((size_t)j * BB + b) * II);
        floatx4 c0 = {0.f, 0.f, 0.f, 0.f};
        floatx4 u4 = __builtin_amdgcn_mfma_f32_16x16x32_bf16(a, xv, c0, 0, 0, 0);
        float e  = E[((size_t)k * JJ + j) * BB + b];
        float Sv = S[j * BB + b];
        float bj = bias[k * JJ + j];
        float c  = fmaf(e, __builtin_amdgcn_rcpf(Sv), bj);
#pragma unroll
        for (int r = 0; r < 4; ++r) sc[r] = fmaf(u4[r], c, sc[r]);
    }
#pragma unroll
    for (int r = 0; r < 4; ++r)
        unsafeAtomicAdd(&sacc[(k * ZZ + g * 4 + r) * BB + b], sc[r] * 0.25f);
}

// ---- Pass D: squash, sacc[k][z][b] -> out[b][k][z] ----
extern "C" __global__ __launch_bounds__(256)
void kD(const float* __restrict__ sacc, float* __restrict__ out) {
    int p = blockIdx.x * blockDim.x + threadIdx.x;
    if (p >= KK * BB) return;
    int k = p >> 7;
    int b = p & 127;
    float v[ZZ];
    float nsq = 0.f;
#pragma unroll
    for (int z = 0; z < ZZ; ++z) {
        v[z] = sacc[(k * ZZ + z) * BB + b];
        nsq  = fmaf(v[z], v[z], nsq);
    }
    float n = sqrtf(nsq);
    float scale = (1.f - 1.f / (__expf(n) + 1e-20f)) / (n + 1e-20f);
#pragma unroll
    for (int z = 0; z < ZZ; ++z)
        out[((size_t)b * KK + k) * ZZ + z] = v[z] * scale;
}

extern "C" void kernel_launch(void* const* d_in, const int* in_sizes, int n_in,
                              void* d_out, int out_size, void* d_ws, size_t ws_size,
                              hipStream_t stream) {
    const float* x    = (const float*)d_in[0];
    const float* W    = (const float*)d_in[1];
    const float* bias = (const float*)d_in[2];
    float*       out  = (float*)d_out;

    float* ws   = (float*)d_ws;
    float* usum = ws;                    // [K][Z][B]
    float* S    = ws + N_USUM;           // [J][B]
    float* sacc = ws + N_USUM + N_S;     // [K][Z][B]
    float* E    = ws + N_ACC;            // [K][J][B]
    __hip_bfloat16* xbf = (__hip_bfloat16*)(ws + N_ACC + N_E);   // [J][B][I]
    __hip_bfloat16* Wt  = xbf + (size_t)N_XBF;                   // [K][J][Z][I]

    hipMemsetAsync(d_ws, 0, (size_t)N_ACC * sizeof(float), stream);

    kX<<<(JJ * BB) / 256, 256, 0, stream>>>(x, xbf);
    kW<<<(KK * JJ * ZZ) / 256, 256, 0, stream>>>(W, Wt);

    kA<<<dim3(8, KK, 16), 64, 0, stream>>>(xbf, Wt, usum);
    kB<<<dim3(8, KK, 18), 64, 0, stream>>>(xbf, Wt, usum, S, E);
    kC<<<dim3(8, KK, 12), 64, 0, stream>>>(xbf, Wt, bias, S, E, sacc);
    kD<<<(KK * BB + 255) / 256, 256, 0, stream>>>(sacc, out);
}